// Round 13
// baseline (400.938 us; speedup 1.0000x reference)
//
#include <hip/hip_runtime.h>

#define NN 50000
#define NE 800000
#define EPS 1e-5f

typedef __attribute__((ext_vector_type(8))) short s16x8;
typedef __attribute__((ext_vector_type(4))) short s16x4;
typedef __attribute__((ext_vector_type(4))) float f32x4;

// ---------------------------------------------------------------------------
// ws layout (round-1-proven >= 307,204,096 bytes):
//   0        : st, 1024 floats (4 KB) — A/C coefficient slots
//   4096     : xbuf bf16 [E][64] (102,400,000 B); RAW x = ef@We+be.
//              Dead after k_y_stats; startF (int[NN+1]) @+4096 and
//              pSQn (32x128 f32) @+266240 overlay it.
//   102404096: ybuf bf16 [E][128], rows permuted to dst-sorted slot order.
// st float offsets: 512 A_e[64], 576 C_e[64], 640 A_y[128], 768 C_y[128],
//                   896 A_n[64], 960 C_n[64]
// d_out (12.8 MB) scratch until k_gather writes agg:
//   BT @0 (49152), BTe @49152 (8192), biasY @57344 (512), cnt @57856 (200000),
//   cur @257856 (200000), slot @457856 (3200000), start_tmp @3657856 (200004),
//   nfb @3857920 (6400000), pSQe @10257920 (16384), pSQy @10274304 (32768)
// NOTES (experiment ledger):
//  r7: 2-tile reg-prefetch y_stats + __launch_bounds__(512,6) spilled
//      (VGPR stuck at 40, FETCH+143MB/WRITE+272MB scratch). r13 retests the
//      SAME pipeline at __launch_bounds__(512) — LDS caps occupancy anyway.
//  r9: 64-edge retile regressed. r10: slot-order iteration regressed.
//  r11: fused slot atomics regressed. r12: r8 config reproduced (385us).
// ---------------------------------------------------------------------------

__device__ __forceinline__ short f2bf(float f) {
    unsigned u = __builtin_bit_cast(unsigned, f);
    unsigned r = (u + 0x7FFFu + ((u >> 16) & 1u)) >> 16;
    return (short)r;
}
__device__ __forceinline__ float bf2f(short s) {
    unsigned u = ((unsigned)(unsigned short)s) << 16;
    return __builtin_bit_cast(float, u);
}
// cheap transcendentals: v_exp/v_log/v_rcp based (tolerance is ~2%)
__device__ __forceinline__ float silu_f(float x) {
    return x * __builtin_amdgcn_rcpf(1.0f + __expf(-x));
}
__device__ __forceinline__ float softplus_f(float x) {
    float t = __expf(-fabsf(x));
    return fmaxf(x, 0.0f) + __logf(1.0f + t);
}
// XOR swizzle for row-major [*][192]-short LDS tile (16 B-slot granularity).
__device__ __forceinline__ int swz(int row, int col) {
    return row * 192 + (col ^ ((row & 7) << 3));
}

// ------------- fused init: hist | nfb | prep | pSQ-zero ----------------------
__global__ void k_init(const int* __restrict__ dst, int* __restrict__ cnt,
                       const float* __restrict__ nf, short* __restrict__ nfb,
                       const float* __restrict__ Wm, const float* __restrict__ Ws,
                       const float* __restrict__ We, const float* __restrict__ bm,
                       const float* __restrict__ bs, short* __restrict__ BT,
                       short* __restrict__ BTe, float* __restrict__ biasY,
                       float* __restrict__ pSQ)
{
    const int b = blockIdx.x;
    if (b < 3125) {                                      // hist
        int e = b * 256 + threadIdx.x;
        if (e < NE) atomicAdd(&cnt[dst[e]], 1);
    } else if (b < 3125 + 1563) {                        // nfb
        long i = (long)(b - 3125) * 256 + threadIdx.x;   // s16x8 index
        if (i >= (long)NN * 64 / 8) return;
        float4 a = ((const float4*)nf)[i * 2];
        float4 c = ((const float4*)nf)[i * 2 + 1];
        s16x8 o;
        o[0] = f2bf(a.x); o[1] = f2bf(a.y); o[2] = f2bf(a.z); o[3] = f2bf(a.w);
        o[4] = f2bf(c.x); o[5] = f2bf(c.y); o[6] = f2bf(c.z); o[7] = f2bf(c.w);
        ((s16x8*)nfb)[i] = o;
    } else if (b < 3125 + 1563 + 113) {                  // prep
        int i = (b - 3125 - 1563) * 256 + threadIdx.x;
        if (i < 24576) {
            int n = i / 192, k = i % 192;
            float w = (n < 64) ? Wm[k * 64 + n] : Ws[k * 64 + (n - 64)];
            BT[n * 192 + k] = f2bf(w);
        } else if (i < 28672) {
            int j = i - 24576;
            int n = j >> 6, k = j & 63;
            BTe[n * 64 + k] = f2bf(We[k * 64 + n]);
        } else if (i < 28800) {
            int j = i - 28672;
            biasY[j] = (j < 64) ? bm[j] : bs[j - 64];
        }
    } else {                                             // zero pSQe+pSQy
        int i = (b - 3125 - 1563 - 113) * 256 + threadIdx.x;
        if (i < 12288) pSQ[i] = 0.f;                     // 49152 B contiguous
    }
}

// ------------- CSR scan + slot ----------------------------------------------
__global__ void k_scan(const int* __restrict__ cnt, int* __restrict__ start_tmp,
                       int* __restrict__ cur)
{
    __shared__ int ps[256];
    const int t = threadIdx.x;
    const int CH = 196;                                  // 256*196 = 50176 >= NN
    int base = t * CH;
    int sum = 0;
    for (int i = 0; i < CH; i += 4) {
        int idx = base + i;
        if (idx < NN) { int4 v = *(const int4*)&cnt[idx]; sum += v.x + v.y + v.z + v.w; }
    }
    ps[t] = sum;
    __syncthreads();
    for (int off = 1; off < 256; off <<= 1) {            // inclusive scan
        int v = (t >= off) ? ps[t - off] : 0;
        __syncthreads();
        ps[t] += v;
        __syncthreads();
    }
    int run = (t == 0) ? 0 : ps[t - 1];                  // exclusive prefix
    for (int i = 0; i < CH; i += 4) {
        int idx = base + i;
        if (idx < NN) {
            int4 v = *(const int4*)&cnt[idx];
            int4 o; o.x = run; o.y = run + v.x; o.z = o.y + v.y; o.w = o.z + v.z;
            *(int4*)&start_tmp[idx] = o;
            *(int4*)&cur[idx] = o;
            run = o.w + v.w;
        }
    }
    if (t == 255) start_tmp[NN] = run;                   // == NE
}

__global__ void k_slot(const int* __restrict__ dst, int* __restrict__ cur,
                       int* __restrict__ slot)
{
    int e = blockIdx.x * 256 + threadIdx.x;
    if (e < NE) slot[e] = atomicAdd(&cur[dst[e]], 1);
}

// ------------- BN finalize from 32 replicated partial buckets ----------------
__global__ void k_fin_r(const float* __restrict__ P, const float* __restrict__ g,
                        const float* __restrict__ b, float inv_cnt, int ncols,
                        float* __restrict__ A, float* __restrict__ C)
{
    int j = threadIdx.x;
    if (j >= ncols) return;
    float S = 0.f, Q = 0.f;
    for (int r = 0; r < 32; ++r) {
        S += P[r * 2 * ncols + j];
        Q += P[r * 2 * ncols + ncols + j];
    }
    float m = S * inv_cnt;
    float v = Q * inv_cnt - m * m;
    float a = g[j] * rsqrtf(v + EPS);
    A[j] = a;
    C[j] = b[j] - m * a;
}

// merged: blocks 0..211 copy startF + zero pSQn; block 212 finalizes y-BNs
__global__ void k_post(const int* __restrict__ start_tmp, int* __restrict__ startF,
                       float* __restrict__ pSQn, const float* __restrict__ P,
                       const float* __restrict__ gm, const float* __restrict__ bem,
                       const float* __restrict__ gs, const float* __restrict__ bes,
                       float* __restrict__ A, float* __restrict__ C)
{
    const int b = blockIdx.x;
    if (b < 212) {
        int i = b * 256 + threadIdx.x;
        if (i <= NN) startF[i] = start_tmp[i];
        int j = i - (NN + 1);
        if (j >= 0 && j < 4096) pSQn[j] = 0.f;
    } else {
        int j = threadIdx.x;
        if (j < 128) {
            float S = 0.f, Q = 0.f;
            for (int r = 0; r < 32; ++r) {
                S += P[r * 256 + j];
                Q += P[r * 256 + 128 + j];
            }
            float g = (j < 64) ? gm[j] : gs[j - 64];
            float bb = (j < 64) ? bem[j] : bes[j - 64];
            float m = S * (1.0f / NE);
            float v = Q * (1.0f / NE) - m * m;
            float a = g * rsqrtf(v + EPS);
            A[j] = a;
            C[j] = bb - m * a;
        }
    }
}

// ------------- Phase 1: x = ef @ W_e + b_e; 2-tile pipelined -----------------
// 512 threads, 8 waves (4x2 grid of 32x32); 256 edges/block in 2 tiles.
__global__ __launch_bounds__(512, 8) void k_xe_m(
    const float* __restrict__ ef, const short* __restrict__ BTe,
    const float* __restrict__ be_, float* __restrict__ pSQe,
    short* __restrict__ xbuf)
{
    __shared__ short sA[128][72];
    __shared__ short sB[64][72];
    __shared__ float sSQ[128];
    __shared__ float sBe[64];
    const int tx = threadIdx.x;
    const long e00 = (long)blockIdx.x * 256;
    const int e = tx >> 2, q4 = tx & 3;

    float4 rf0, rf1, rf2, rf3;                           // prefetch tile 0
    {
        const float* p = ef + (e00 + e) * 64 + q4 * 16;
        rf0 = *(const float4*)(p + 0);  rf1 = *(const float4*)(p + 4);
        rf2 = *(const float4*)(p + 8);  rf3 = *(const float4*)(p + 12);
    }
    if (tx < 128) sSQ[tx] = 0.f;
    if (tx < 64) sBe[tx] = be_[tx];
    {                                                    // stage W_e^T once
        int n = tx >> 3, c = (tx & 7) * 8;
        *(s16x8*)&sB[n][c] = ((const s16x8*)BTe)[tx];
    }

    const int w = tx >> 6, lane = tx & 63, lr = lane & 15, lg = lane >> 4;
    const int wr = w >> 1, wc = w & 1;

    #pragma unroll
    for (int t = 0; t < 2; ++t) {
        {                                                // regs -> LDS (bf16)
            s16x4 w0, w1, w2, w3;
            w0.x = f2bf(rf0.x); w0.y = f2bf(rf0.y); w0.z = f2bf(rf0.z); w0.w = f2bf(rf0.w);
            w1.x = f2bf(rf1.x); w1.y = f2bf(rf1.y); w1.z = f2bf(rf1.z); w1.w = f2bf(rf1.w);
            w2.x = f2bf(rf2.x); w2.y = f2bf(rf2.y); w2.z = f2bf(rf2.z); w2.w = f2bf(rf2.w);
            w3.x = f2bf(rf3.x); w3.y = f2bf(rf3.y); w3.z = f2bf(rf3.z); w3.w = f2bf(rf3.w);
            *(s16x4*)&sA[e][q4 * 16 + 0]  = w0;
            *(s16x4*)&sA[e][q4 * 16 + 4]  = w1;
            *(s16x4*)&sA[e][q4 * 16 + 8]  = w2;
            *(s16x4*)&sA[e][q4 * 16 + 12] = w3;
        }
        if (t == 0) {                                    // prefetch tile 1
            const float* p = ef + (e00 + 128 + e) * 64 + q4 * 16;
            rf0 = *(const float4*)(p + 0);  rf1 = *(const float4*)(p + 4);
            rf2 = *(const float4*)(p + 8);  rf3 = *(const float4*)(p + 12);
        }
        __syncthreads();

        f32x4 acc[2][2];
        #pragma unroll
        for (int m = 0; m < 2; ++m)
            #pragma unroll
            for (int n = 0; n < 2; ++n)
                #pragma unroll
                for (int q = 0; q < 4; ++q) acc[m][n][q] = 0.f;

        #pragma unroll
        for (int ks = 0; ks < 2; ++ks) {
            s16x8 a[2], b[2];
            #pragma unroll
            for (int m = 0; m < 2; ++m) a[m] = *(const s16x8*)&sA[32 * wr + 16 * m + lr][ks * 32 + 8 * lg];
            #pragma unroll
            for (int n = 0; n < 2; ++n) b[n] = *(const s16x8*)&sB[32 * wc + 16 * n + lr][ks * 32 + 8 * lg];
            #pragma unroll
            for (int m = 0; m < 2; ++m)
                #pragma unroll
                for (int n = 0; n < 2; ++n)
                    acc[m][n] = __builtin_amdgcn_mfma_f32_16x16x32_bf16(a[m], b[n], acc[m][n], 0, 0, 0);
        }
        __syncthreads();                                 // frag reads done

        #pragma unroll
        for (int n = 0; n < 2; ++n) {                    // bias + stats + x->LDS
            int col = 32 * wc + 16 * n + lr;
            float b = sBe[col];
            float s = 0.f, q = 0.f;
            #pragma unroll
            for (int m = 0; m < 2; ++m)
                #pragma unroll
                for (int r = 0; r < 4; ++r) {
                    float y = acc[m][n][r] + b;
                    s += y; q += y * y;
                    int row = 32 * wr + 16 * m + 4 * lg + r;
                    ((short*)sA)[row * 64 + col] = f2bf(y);
                }
            s += __shfl_xor(s, 16); s += __shfl_xor(s, 32);
            q += __shfl_xor(q, 16); q += __shfl_xor(q, 32);
            if (lg == 0) { atomicAdd(&sSQ[col], s); atomicAdd(&sSQ[64 + col], q); }
        }
        __syncthreads();
        #pragma unroll
        for (int i = tx; i < 1024; i += 512)             // store xbuf tile
            ((s16x8*)(xbuf + (e00 + t * 128) * 64))[i] = ((const s16x8*)sA)[i];
        __syncthreads();                                 // protect sA reuse
    }
    if (tx < 128) atomicAdd(&pSQe[(blockIdx.x & 31) * 128 + tx], sSQ[tx]);
}

// ------------- Phase 2: y = h_combine @ [W_m|W_s] + bias; stats; store -------
// r13: 2-tile register-prefetch pipeline (r7 structure) at permissive
// __launch_bounds__(512) — r7's spill was the (512,6) bound, not the idea.
// 512 threads, 8 waves (2x4 grid; wave computes 64x32). 256 edges/block.
__global__ __launch_bounds__(512) void k_y_stats(
    const short* __restrict__ nfb, const int* __restrict__ src,
    const int* __restrict__ dst, const short* __restrict__ xbuf,
    const short* __restrict__ BT, const float* __restrict__ biasY,
    const int* __restrict__ slot, const float* __restrict__ st,
    float* __restrict__ pSQy, short* __restrict__ ybuf)
{
    __shared__ s16x8 sAv[128 * 24];                      // [128][192] shorts
    short* sA = (short*)sAv;
    __shared__ float sSQ[256];
    __shared__ float sAeCe[128];
    __shared__ float sBias[128];
    __shared__ int   sSlot[256];

    const int tx = threadIdx.x;
    const long e00 = (long)blockIdx.x * 256;
    const int e = tx >> 2, q4 = tx & 3;

    s16x8 ps0, ps1, pd0, pd1, px0, px1;                  // prefetch tile 0
    {
        int sn = src[e00 + e], dn = dst[e00 + e];
        const short* ps = nfb + (size_t)sn * 64 + q4 * 16;
        const short* pd = nfb + (size_t)dn * 64 + q4 * 16;
        const short* px = xbuf + (size_t)(e00 + e) * 64 + q4 * 16;
        ps0 = *(const s16x8*)ps;       ps1 = *(const s16x8*)(ps + 8);
        pd0 = *(const s16x8*)pd;       pd1 = *(const s16x8*)(pd + 8);
        px0 = *(const s16x8*)px;       px1 = *(const s16x8*)(px + 8);
    }
    if (tx < 256) { sSQ[tx] = 0.f; sSlot[tx] = slot[e00 + tx]; }
    if (tx < 128) { sAeCe[tx] = st[512 + tx]; sBias[tx] = biasY[tx]; }
    __syncthreads();                                     // sAeCe visible

    const int w = tx >> 6, lane = tx & 63, lr = lane & 15, lg = lane >> 4;
    const int wr = w >> 2, wc = w & 3;                   // 2 x 4 wave grid
    const s16x8* Bg = (const s16x8*)BT;                  // [128 rows][24 frags]
    const int brow = (32 * wc + lr) * 24 + lg;

    #pragma unroll
    for (int t = 0; t < 2; ++t) {
        {                                                // regs -> LDS
            *(s16x8*)&sA[swz(e, q4 * 16 + 0)]      = ps0;
            *(s16x8*)&sA[swz(e, q4 * 16 + 8)]      = ps1;
            *(s16x8*)&sA[swz(e, 64 + q4 * 16 + 0)] = pd0;
            *(s16x8*)&sA[swz(e, 64 + q4 * 16 + 8)] = pd1;
            s16x8 hv0, hv1;
            #pragma unroll
            for (int k = 0; k < 8; ++k) {
                int j = q4 * 16 + k;
                hv0[k] = f2bf(silu_f(fmaf(bf2f(px0[k]), sAeCe[j], sAeCe[64 + j])));
                hv1[k] = f2bf(silu_f(fmaf(bf2f(px1[k]), sAeCe[j + 8], sAeCe[64 + j + 8])));
            }
            *(s16x8*)&sA[swz(e, 128 + q4 * 16 + 0)] = hv0;
            *(s16x8*)&sA[swz(e, 128 + q4 * 16 + 8)] = hv1;
        }
        if (t == 0) {                                    // prefetch tile 1
            int sn = src[e00 + 128 + e], dn = dst[e00 + 128 + e];
            const short* ps = nfb + (size_t)sn * 64 + q4 * 16;
            const short* pd = nfb + (size_t)dn * 64 + q4 * 16;
            const short* px = xbuf + (size_t)(e00 + 128 + e) * 64 + q4 * 16;
            ps0 = *(const s16x8*)ps;   ps1 = *(const s16x8*)(ps + 8);
            pd0 = *(const s16x8*)pd;   pd1 = *(const s16x8*)(pd + 8);
            px0 = *(const s16x8*)px;   px1 = *(const s16x8*)(px + 8);
        }
        __syncthreads();

        f32x4 acc[4][2];
        #pragma unroll
        for (int m = 0; m < 4; ++m)
            #pragma unroll
            for (int n = 0; n < 2; ++n)
                #pragma unroll
                for (int q = 0; q < 4; ++q) acc[m][n][q] = 0.f;

        #pragma unroll
        for (int ks = 0; ks < 6; ++ks) {
            s16x8 a[4], b[2];
            #pragma unroll
            for (int m = 0; m < 4; ++m)
                a[m] = *(const s16x8*)&sA[swz(64 * wr + 16 * m + lr, ks * 32 + 8 * lg)];
            #pragma unroll
            for (int n = 0; n < 2; ++n)
                b[n] = Bg[brow + 384 * n + 4 * ks];
            #pragma unroll
            for (int m = 0; m < 4; ++m)
                #pragma unroll
                for (int n = 0; n < 2; ++n)
                    acc[m][n] = __builtin_amdgcn_mfma_f32_16x16x32_bf16(a[m], b[n], acc[m][n], 0, 0, 0);
        }
        __syncthreads();                                 // frag reads done

        #pragma unroll
        for (int n = 0; n < 2; ++n) {                    // bias + stats + y->LDS
            int col = 32 * wc + 16 * n + lr;
            float b = sBias[col];
            float s = 0.f, q = 0.f;
            #pragma unroll
            for (int m = 0; m < 4; ++m)
                #pragma unroll
                for (int r = 0; r < 4; ++r) {
                    float y = acc[m][n][r] + b;
                    s += y; q += y * y;
                    int row = 64 * wr + 16 * m + 4 * lg + r;
                    sA[row * 192 + (col ^ ((row & 7) << 3))] = f2bf(y);
                }
            s += __shfl_xor(s, 16); s += __shfl_xor(s, 32);
            q += __shfl_xor(q, 16); q += __shfl_xor(q, 32);
            if (lg == 0) { atomicAdd(&sSQ[col], s); atomicAdd(&sSQ[128 + col], q); }
        }
        __syncthreads();
        #pragma unroll
        for (int i = tx; i < 2048; i += 512) {           // permuted row store
            int row = i >> 4, frag = i & 15;
            s16x8 v = *(const s16x8*)&sA[swz(row, frag * 8)];
            *(s16x8*)(ybuf + (size_t)sSlot[t * 128 + row] * 128 + frag * 8) = v;
        }
        __syncthreads();                                 // protect sA reuse
    }
    if (tx < 256) atomicAdd(&pSQy[(blockIdx.x & 31) * 256 + tx], sSQ[tx]);
}

// ------------- Phase 3: vectorized gather + fused node BN stats --------------
// One wave per node; lane owns 8 cols (g=lane&7), rows split 8-way (rg).
__global__ __launch_bounds__(256) void k_gather(
    const short* __restrict__ ybuf, const int* __restrict__ startF,
    const float* __restrict__ st, float* __restrict__ pSQn,
    float* __restrict__ agg)
{
    __shared__ float sA_[128], sC_[128];
    __shared__ float sS[4][64], sQv[4][64];
    const int tx = threadIdx.x;
    if (tx < 128) { sA_[tx] = st[640 + tx]; sC_[tx] = st[768 + tx]; }
    __syncthreads();
    const int w = tx >> 6, l = tx & 63, g = l & 7, rg = l >> 3;
    const int n = blockIdx.x * 4 + w;
    const int s = startF[n], e2 = startF[n + 1];
    float am[8], cm[8], as2[8], cs2[8];
    #pragma unroll
    for (int t = 0; t < 8; ++t) {
        am[t] = sA_[8 * g + t];       cm[t] = sC_[8 * g + t];
        as2[t] = sA_[64 + 8 * g + t]; cs2[t] = sC_[64 + 8 * g + t];
    }
    float acc[8];
    #pragma unroll
    for (int t = 0; t < 8; ++t) acc[t] = 0.f;
    const short* base = ybuf + (size_t)s * 128;
    const int deg = e2 - s;
    for (int i = rg; i < deg; i += 8) {
        s16x8 ym8 = *(const s16x8*)(base + (size_t)i * 128 + g * 8);
        s16x8 ys8 = *(const s16x8*)(base + (size_t)i * 128 + 64 + g * 8);
        #pragma unroll
        for (int t = 0; t < 8; ++t)
            acc[t] += silu_f(fmaf(bf2f(ym8[t]), am[t], cm[t]))
                    * softplus_f(fmaf(bf2f(ys8[t]), as2[t], cs2[t]));
    }
    #pragma unroll
    for (int t = 0; t < 8; ++t) {                        // reduce row-groups
        acc[t] += __shfl_xor(acc[t], 8);
        acc[t] += __shfl_xor(acc[t], 16);
        acc[t] += __shfl_xor(acc[t], 32);
    }
    if (l < 8) {                                         // l == g here
        float4 f0 = {acc[0], acc[1], acc[2], acc[3]};
        float4 f1 = {acc[4], acc[5], acc[6], acc[7]};
        *(float4*)&agg[(size_t)n * 64 + g * 8] = f0;
        *(float4*)&agg[(size_t)n * 64 + g * 8 + 4] = f1;
        #pragma unroll
        for (int t = 0; t < 8; ++t) {
            sS[w][g * 8 + t] = acc[t];
            sQv[w][g * 8 + t] = acc[t] * acc[t];
        }
    }
    __syncthreads();
    if (tx < 64) {
        float s2 = sS[0][tx] + sS[1][tx] + sS[2][tx] + sS[3][tx];
        atomicAdd(&pSQn[(blockIdx.x & 31) * 128 + tx], s2);
    } else if (tx < 128) {
        int jj = tx - 64;
        float q2 = sQv[0][jj] + sQv[1][jj] + sQv[2][jj] + sQv[3][jj];
        atomicAdd(&pSQn[(blockIdx.x & 31) * 128 + 64 + jj], q2);
    }
}

// ------------- Phase 5: out = softplus(bn_n(agg) + nf), in place -------------
__global__ __launch_bounds__(256) void k_out(float* __restrict__ outagg,
                                             const float* __restrict__ nf,
                                             const float* __restrict__ st)
{
    long t = (long)blockIdx.x * 256 + threadIdx.x;
    int j = (int)(t & 63);
    float a = outagg[t];
    outagg[t] = softplus_f(fmaf(a, st[896 + j], st[960 + j]) + nf[t]);
}

extern "C" void kernel_launch(void* const* d_in, const int* in_sizes, int n_in,
                              void* d_out, int out_size, void* d_ws, size_t ws_size,
                              hipStream_t stream)
{
    (void)in_sizes; (void)n_in; (void)out_size; (void)ws_size;
    const float* nf  = (const float*)d_in[0];
    const float* ef  = (const float*)d_in[1];
    const int*   src = (const int*)d_in[2];
    const int*   dst = (const int*)d_in[3];
    const float* We  = (const float*)d_in[4];
    const float* be_ = (const float*)d_in[5];
    const float* ge  = (const float*)d_in[6];
    const float* bee = (const float*)d_in[7];
    const float* Wm  = (const float*)d_in[8];
    const float* bm  = (const float*)d_in[9];
    const float* gm  = (const float*)d_in[10];
    const float* bem = (const float*)d_in[11];
    const float* Ws  = (const float*)d_in[12];
    const float* bs  = (const float*)d_in[13];
    const float* gs  = (const float*)d_in[14];
    const float* bes = (const float*)d_in[15];
    const float* gn  = (const float*)d_in[16];
    const float* ben = (const float*)d_in[17];

    // ws layout
    float* st    = (float*)d_ws;
    short* xbuf  = (short*)((char*)d_ws + 4096);
    int*   startF= (int*)((char*)d_ws + 4096);            // overlays dead xbuf
    float* pSQn  = (float*)((char*)d_ws + 266240);        // overlays dead xbuf
    short* ybuf  = (short*)((char*)d_ws + 4096 + 102400000);

    // d_out scratch (dead before k_gather)
    char* ob = (char*)d_out;
    short* BT        = (short*)ob;
    short* BTe       = (short*)(ob + 49152);
    float* biasY     = (float*)(ob + 57344);
    int*   cnt       = (int*)(ob + 57856);
    int*   cur       = (int*)(ob + 257856);
    int*   slot      = (int*)(ob + 457856);
    int*   start_tmp = (int*)(ob + 3657856);
    short* nfb       = (short*)(ob + 3857920);
    float* pSQe      = (float*)(ob + 10257920);           // pSQy contiguous after
    float* agg       = (float*)d_out;

    hipMemsetAsync(cnt, 0, 200000, stream);

    // k_init: 3125 hist + 1563 nfb + 113 prep + 48 pSQ-zero = 4849 blocks
    k_init<<<4849, 256, 0, stream>>>(dst, cnt, nf, nfb,
                                     Wm, Ws, We, bm, bs, BT, BTe, biasY, pSQe);
    k_scan<<<1, 256, 0, stream>>>(cnt, start_tmp, cur);
    k_slot<<<3125, 256, 0, stream>>>(dst, cur, slot);

    k_xe_m<<<NE / 256, 512, 0, stream>>>(ef, BTe, be_, pSQe, xbuf);
    k_fin_r<<<1, 64, 0, stream>>>(pSQe, ge, bee, 1.0f / NE, 64, st + 512, st + 576);

    k_y_stats<<<NE / 256, 512, 0, stream>>>(nfb, src, dst, xbuf, BT, biasY, slot, st,
                                            pSQe + 4096 /* pSQy */, ybuf);

    // copy startF (xbuf now dead) + zero pSQn + finalize y-BNs, one launch
    k_post<<<213, 256, 0, stream>>>(start_tmp, startF, pSQn, pSQe + 4096,
                                    gm, bem, gs, bes, st + 640, st + 768);

    k_gather<<<NN / 4, 256, 0, stream>>>(ybuf, startF, st, pSQn, agg);
    k_fin_r<<<1, 64, 0, stream>>>(pSQn, gn, ben, 1.0f / NN, 64, st + 896, st + 960);

    k_out<<<NN * 64 / 256, 256, 0, stream>>>(agg, nf, st);
}

// Round 14
// 384.862 us; speedup vs baseline: 1.0418x; 1.0418x over previous
//
#include <hip/hip_runtime.h>

#define NN 50000
#define NE 800000
#define EPS 1e-5f

typedef __attribute__((ext_vector_type(8))) short s16x8;
typedef __attribute__((ext_vector_type(4))) short s16x4;
typedef __attribute__((ext_vector_type(4))) float f32x4;

// ---------------------------------------------------------------------------
// ws layout (round-1-proven >= 307,204,096 bytes):
//   0        : st, 1024 floats (4 KB) — A/C coefficient slots
//   4096     : xbuf bf16 [E][64] (102,400,000 B); RAW x = ef@We+be.
//              Dead after k_y_stats; startF (int[NN+1]) @+4096 and
//              pSQn (32x128 f32) @+266240 overlay it.
//   102404096: ybuf bf16 [E][128], rows permuted to dst-sorted slot order.
// st float offsets: 512 A_e[64], 576 C_e[64], 640 A_y[128], 768 C_y[128],
//                   896 A_n[64], 960 C_n[64]
// d_out (12.8 MB) scratch until k_gather writes agg:
//   BT @0 (49152), BTe @49152 (8192), biasY @57344 (512), cnt @57856 (200000),
//   cur @257856 (200000), slot @457856 (3200000), start_tmp @3657856 (200004),
//   nfb @3857920 (6400000), pSQe @10257920 (16384), pSQy @10274304 (32768)
// NOTES (experiment ledger — final):
//  r7:  reg-prefetch + (512,6) bound -> scratch spill, 2x HBM. REJECTED.
//  r9:  64-edge retile -> fixed costs doubled, occupancy flat. REJECTED.
//  r10: slot-order iteration -> +49MB FETCH (random xbuf reads). REJECTED.
//  r11: fused slot atomics -> cur-contention on barrier drain. REJECTED.
//  r13: reg-prefetch + permissive bound -> no spill (VGPR 64) but occ 60->40%,
//       +20us: prefetch live-ranges across barriers serialize waves. REJECTED.
//  r12: THIS config, measured 385.2us (r8 replica 388.1; noise ±1%).
//       k_y_stats 133us @ 2.6TB/s / occ 60% is the structure's ceiling.
// ---------------------------------------------------------------------------

__device__ __forceinline__ short f2bf(float f) {
    unsigned u = __builtin_bit_cast(unsigned, f);
    unsigned r = (u + 0x7FFFu + ((u >> 16) & 1u)) >> 16;
    return (short)r;
}
__device__ __forceinline__ float bf2f(short s) {
    unsigned u = ((unsigned)(unsigned short)s) << 16;
    return __builtin_bit_cast(float, u);
}
// cheap transcendentals: v_exp/v_log/v_rcp based (tolerance is ~2%)
__device__ __forceinline__ float silu_f(float x) {
    return x * __builtin_amdgcn_rcpf(1.0f + __expf(-x));
}
__device__ __forceinline__ float softplus_f(float x) {
    float t = __expf(-fabsf(x));
    return fmaxf(x, 0.0f) + __logf(1.0f + t);
}
// XOR swizzle for row-major [*][192]-short LDS tile (16 B-slot granularity).
__device__ __forceinline__ int swz(int row, int col) {
    return row * 192 + (col ^ ((row & 7) << 3));
}

// ------------- fused init: hist | nfb | prep | pSQ-zero ----------------------
__global__ void k_init(const int* __restrict__ dst, int* __restrict__ cnt,
                       const float* __restrict__ nf, short* __restrict__ nfb,
                       const float* __restrict__ Wm, const float* __restrict__ Ws,
                       const float* __restrict__ We, const float* __restrict__ bm,
                       const float* __restrict__ bs, short* __restrict__ BT,
                       short* __restrict__ BTe, float* __restrict__ biasY,
                       float* __restrict__ pSQ)
{
    const int b = blockIdx.x;
    if (b < 3125) {                                      // hist
        int e = b * 256 + threadIdx.x;
        if (e < NE) atomicAdd(&cnt[dst[e]], 1);
    } else if (b < 3125 + 1563) {                        // nfb
        long i = (long)(b - 3125) * 256 + threadIdx.x;   // s16x8 index
        if (i >= (long)NN * 64 / 8) return;
        float4 a = ((const float4*)nf)[i * 2];
        float4 c = ((const float4*)nf)[i * 2 + 1];
        s16x8 o;
        o[0] = f2bf(a.x); o[1] = f2bf(a.y); o[2] = f2bf(a.z); o[3] = f2bf(a.w);
        o[4] = f2bf(c.x); o[5] = f2bf(c.y); o[6] = f2bf(c.z); o[7] = f2bf(c.w);
        ((s16x8*)nfb)[i] = o;
    } else if (b < 3125 + 1563 + 113) {                  // prep
        int i = (b - 3125 - 1563) * 256 + threadIdx.x;
        if (i < 24576) {
            int n = i / 192, k = i % 192;
            float w = (n < 64) ? Wm[k * 64 + n] : Ws[k * 64 + (n - 64)];
            BT[n * 192 + k] = f2bf(w);
        } else if (i < 28672) {
            int j = i - 24576;
            int n = j >> 6, k = j & 63;
            BTe[n * 64 + k] = f2bf(We[k * 64 + n]);
        } else if (i < 28800) {
            int j = i - 28672;
            biasY[j] = (j < 64) ? bm[j] : bs[j - 64];
        }
    } else {                                             // zero pSQe+pSQy
        int i = (b - 3125 - 1563 - 113) * 256 + threadIdx.x;
        if (i < 12288) pSQ[i] = 0.f;                     // 49152 B contiguous
    }
}

// ------------- CSR scan + slot ----------------------------------------------
__global__ void k_scan(const int* __restrict__ cnt, int* __restrict__ start_tmp,
                       int* __restrict__ cur)
{
    __shared__ int ps[256];
    const int t = threadIdx.x;
    const int CH = 196;                                  // 256*196 = 50176 >= NN
    int base = t * CH;
    int sum = 0;
    for (int i = 0; i < CH; i += 4) {
        int idx = base + i;
        if (idx < NN) { int4 v = *(const int4*)&cnt[idx]; sum += v.x + v.y + v.z + v.w; }
    }
    ps[t] = sum;
    __syncthreads();
    for (int off = 1; off < 256; off <<= 1) {            // inclusive scan
        int v = (t >= off) ? ps[t - off] : 0;
        __syncthreads();
        ps[t] += v;
        __syncthreads();
    }
    int run = (t == 0) ? 0 : ps[t - 1];                  // exclusive prefix
    for (int i = 0; i < CH; i += 4) {
        int idx = base + i;
        if (idx < NN) {
            int4 v = *(const int4*)&cnt[idx];
            int4 o; o.x = run; o.y = run + v.x; o.z = o.y + v.y; o.w = o.z + v.z;
            *(int4*)&start_tmp[idx] = o;
            *(int4*)&cur[idx] = o;
            run = o.w + v.w;
        }
    }
    if (t == 255) start_tmp[NN] = run;                   // == NE
}

__global__ void k_slot(const int* __restrict__ dst, int* __restrict__ cur,
                       int* __restrict__ slot)
{
    int e = blockIdx.x * 256 + threadIdx.x;
    if (e < NE) slot[e] = atomicAdd(&cur[dst[e]], 1);
}

// ------------- BN finalize from 32 replicated partial buckets ----------------
__global__ void k_fin_r(const float* __restrict__ P, const float* __restrict__ g,
                        const float* __restrict__ b, float inv_cnt, int ncols,
                        float* __restrict__ A, float* __restrict__ C)
{
    int j = threadIdx.x;
    if (j >= ncols) return;
    float S = 0.f, Q = 0.f;
    for (int r = 0; r < 32; ++r) {
        S += P[r * 2 * ncols + j];
        Q += P[r * 2 * ncols + ncols + j];
    }
    float m = S * inv_cnt;
    float v = Q * inv_cnt - m * m;
    float a = g[j] * rsqrtf(v + EPS);
    A[j] = a;
    C[j] = b[j] - m * a;
}

// merged: blocks 0..211 copy startF + zero pSQn; block 212 finalizes y-BNs
__global__ void k_post(const int* __restrict__ start_tmp, int* __restrict__ startF,
                       float* __restrict__ pSQn, const float* __restrict__ P,
                       const float* __restrict__ gm, const float* __restrict__ bem,
                       const float* __restrict__ gs, const float* __restrict__ bes,
                       float* __restrict__ A, float* __restrict__ C)
{
    const int b = blockIdx.x;
    if (b < 212) {
        int i = b * 256 + threadIdx.x;
        if (i <= NN) startF[i] = start_tmp[i];
        int j = i - (NN + 1);
        if (j >= 0 && j < 4096) pSQn[j] = 0.f;
    } else {
        int j = threadIdx.x;
        if (j < 128) {
            float S = 0.f, Q = 0.f;
            for (int r = 0; r < 32; ++r) {
                S += P[r * 256 + j];
                Q += P[r * 256 + 128 + j];
            }
            float g = (j < 64) ? gm[j] : gs[j - 64];
            float bb = (j < 64) ? bem[j] : bes[j - 64];
            float m = S * (1.0f / NE);
            float v = Q * (1.0f / NE) - m * m;
            float a = g * rsqrtf(v + EPS);
            A[j] = a;
            C[j] = bb - m * a;
        }
    }
}

// ------------- Phase 1: x = ef @ W_e + b_e; 2-tile pipelined -----------------
// 512 threads, 8 waves (4x2 grid of 32x32); 256 edges/block in 2 tiles.
__global__ __launch_bounds__(512, 8) void k_xe_m(
    const float* __restrict__ ef, const short* __restrict__ BTe,
    const float* __restrict__ be_, float* __restrict__ pSQe,
    short* __restrict__ xbuf)
{
    __shared__ short sA[128][72];
    __shared__ short sB[64][72];
    __shared__ float sSQ[128];
    __shared__ float sBe[64];
    const int tx = threadIdx.x;
    const long e00 = (long)blockIdx.x * 256;
    const int e = tx >> 2, q4 = tx & 3;

    float4 rf0, rf1, rf2, rf3;                           // prefetch tile 0
    {
        const float* p = ef + (e00 + e) * 64 + q4 * 16;
        rf0 = *(const float4*)(p + 0);  rf1 = *(const float4*)(p + 4);
        rf2 = *(const float4*)(p + 8);  rf3 = *(const float4*)(p + 12);
    }
    if (tx < 128) sSQ[tx] = 0.f;
    if (tx < 64) sBe[tx] = be_[tx];
    {                                                    // stage W_e^T once
        int n = tx >> 3, c = (tx & 7) * 8;
        *(s16x8*)&sB[n][c] = ((const s16x8*)BTe)[tx];
    }

    const int w = tx >> 6, lane = tx & 63, lr = lane & 15, lg = lane >> 4;
    const int wr = w >> 1, wc = w & 1;

    #pragma unroll
    for (int t = 0; t < 2; ++t) {
        {                                                // regs -> LDS (bf16)
            s16x4 w0, w1, w2, w3;
            w0.x = f2bf(rf0.x); w0.y = f2bf(rf0.y); w0.z = f2bf(rf0.z); w0.w = f2bf(rf0.w);
            w1.x = f2bf(rf1.x); w1.y = f2bf(rf1.y); w1.z = f2bf(rf1.z); w1.w = f2bf(rf1.w);
            w2.x = f2bf(rf2.x); w2.y = f2bf(rf2.y); w2.z = f2bf(rf2.z); w2.w = f2bf(rf2.w);
            w3.x = f2bf(rf3.x); w3.y = f2bf(rf3.y); w3.z = f2bf(rf3.z); w3.w = f2bf(rf3.w);
            *(s16x4*)&sA[e][q4 * 16 + 0]  = w0;
            *(s16x4*)&sA[e][q4 * 16 + 4]  = w1;
            *(s16x4*)&sA[e][q4 * 16 + 8]  = w2;
            *(s16x4*)&sA[e][q4 * 16 + 12] = w3;
        }
        if (t == 0) {                                    // prefetch tile 1
            const float* p = ef + (e00 + 128 + e) * 64 + q4 * 16;
            rf0 = *(const float4*)(p + 0);  rf1 = *(const float4*)(p + 4);
            rf2 = *(const float4*)(p + 8);  rf3 = *(const float4*)(p + 12);
        }
        __syncthreads();

        f32x4 acc[2][2];
        #pragma unroll
        for (int m = 0; m < 2; ++m)
            #pragma unroll
            for (int n = 0; n < 2; ++n)
                #pragma unroll
                for (int q = 0; q < 4; ++q) acc[m][n][q] = 0.f;

        #pragma unroll
        for (int ks = 0; ks < 2; ++ks) {
            s16x8 a[2], b[2];
            #pragma unroll
            for (int m = 0; m < 2; ++m) a[m] = *(const s16x8*)&sA[32 * wr + 16 * m + lr][ks * 32 + 8 * lg];
            #pragma unroll
            for (int n = 0; n < 2; ++n) b[n] = *(const s16x8*)&sB[32 * wc + 16 * n + lr][ks * 32 + 8 * lg];
            #pragma unroll
            for (int m = 0; m < 2; ++m)
                #pragma unroll
                for (int n = 0; n < 2; ++n)
                    acc[m][n] = __builtin_amdgcn_mfma_f32_16x16x32_bf16(a[m], b[n], acc[m][n], 0, 0, 0);
        }
        __syncthreads();                                 // frag reads done

        #pragma unroll
        for (int n = 0; n < 2; ++n) {                    // bias + stats + x->LDS
            int col = 32 * wc + 16 * n + lr;
            float b = sBe[col];
            float s = 0.f, q = 0.f;
            #pragma unroll
            for (int m = 0; m < 2; ++m)
                #pragma unroll
                for (int r = 0; r < 4; ++r) {
                    float y = acc[m][n][r] + b;
                    s += y; q += y * y;
                    int row = 32 * wr + 16 * m + 4 * lg + r;
                    ((short*)sA)[row * 64 + col] = f2bf(y);
                }
            s += __shfl_xor(s, 16); s += __shfl_xor(s, 32);
            q += __shfl_xor(q, 16); q += __shfl_xor(q, 32);
            if (lg == 0) { atomicAdd(&sSQ[col], s); atomicAdd(&sSQ[64 + col], q); }
        }
        __syncthreads();
        #pragma unroll
        for (int i = tx; i < 1024; i += 512)             // store xbuf tile
            ((s16x8*)(xbuf + (e00 + t * 128) * 64))[i] = ((const s16x8*)sA)[i];
        __syncthreads();                                 // protect sA reuse
    }
    if (tx < 128) atomicAdd(&pSQe[(blockIdx.x & 31) * 128 + tx], sSQ[tx]);
}

// ------------- Phase 2: y = h_combine @ [W_m|W_s] + bias; stats; store -------
// r8 proven form: 512 threads, 8 waves (2x4 grid; wave computes 64x32).
// 128 edges/block; slot[] precomputed by k_slot.
__global__ __launch_bounds__(512, 3) void k_y_stats(
    const short* __restrict__ nfb, const int* __restrict__ src,
    const int* __restrict__ dst, const short* __restrict__ xbuf,
    const short* __restrict__ BT, const float* __restrict__ biasY,
    const int* __restrict__ slot, const float* __restrict__ st,
    float* __restrict__ pSQy, short* __restrict__ ybuf)
{
    __shared__ s16x8 sAv[128 * 24];                      // [128][192] shorts
    short* sA = (short*)sAv;
    __shared__ float sSQ[256];
    __shared__ float sAeCe[128];
    __shared__ float sBias[128];
    __shared__ int   sSlot[128];

    const int tx = threadIdx.x;
    const long e0 = (long)blockIdx.x * 128;

    if (tx < 256) sSQ[tx] = 0.f;
    if (tx < 128) {
        sAeCe[tx] = st[512 + tx];
        sBias[tx] = biasY[tx];
        sSlot[tx] = slot[e0 + tx];
    }

    const int e = tx >> 2, q4 = tx & 3;                  // 4 threads/edge
    {                                                    // stage node rows (copies)
        int sn = src[e0 + e], dn = dst[e0 + e];
        const short* ps = nfb + (size_t)sn * 64 + q4 * 16;
        const short* pd = nfb + (size_t)dn * 64 + q4 * 16;
        #pragma unroll
        for (int c = 0; c < 16; c += 8) {
            *(s16x8*)&sA[swz(e, q4 * 16 + c)]      = *(const s16x8*)(ps + c);
            *(s16x8*)&sA[swz(e, 64 + q4 * 16 + c)] = *(const s16x8*)(pd + c);
        }
    }
    __syncthreads();                                     // sAeCe visible
    {                                                    // stage hm = silu(bn_e(x))
        const short* px = xbuf + (size_t)(e0 + e) * 64 + q4 * 16;
        #pragma unroll
        for (int c = 0; c < 16; c += 8) {
            s16x8 xv = *(const s16x8*)(px + c);
            s16x8 hv;
            #pragma unroll
            for (int t = 0; t < 8; ++t) {
                int j = q4 * 16 + c + t;
                float x = bf2f(xv[t]);
                hv[t] = f2bf(silu_f(fmaf(x, sAeCe[j], sAeCe[64 + j])));
            }
            *(s16x8*)&sA[swz(e, 128 + q4 * 16 + c)] = hv;
        }
    }
    __syncthreads();

    const int w = tx >> 6, lane = tx & 63, lr = lane & 15, lg = lane >> 4;
    const int wr = w >> 2, wc = w & 3;                   // 2 x 4 wave grid
    f32x4 acc[4][2];
    for (int m = 0; m < 4; ++m) for (int n = 0; n < 2; ++n)
        for (int q = 0; q < 4; ++q) acc[m][n][q] = 0.f;

    const s16x8* Bg = (const s16x8*)BT;                  // [128 rows][24 frags]
    const int brow = (32 * wc + lr) * 24 + lg;

    #pragma unroll
    for (int ks = 0; ks < 6; ++ks) {
        s16x8 a[4], b[2];
        #pragma unroll
        for (int m = 0; m < 4; ++m)
            a[m] = *(const s16x8*)&sA[swz(64 * wr + 16 * m + lr, ks * 32 + 8 * lg)];
        #pragma unroll
        for (int n = 0; n < 2; ++n)
            b[n] = Bg[brow + 384 * n + 4 * ks];
        #pragma unroll
        for (int m = 0; m < 4; ++m)
            #pragma unroll
            for (int n = 0; n < 2; ++n)
                acc[m][n] = __builtin_amdgcn_mfma_f32_16x16x32_bf16(a[m], b[n], acc[m][n], 0, 0, 0);
    }

    __syncthreads();                                     // all sA frag reads done
    #pragma unroll
    for (int n = 0; n < 2; ++n) {                        // bias + stats + y->LDS
        int col = 32 * wc + 16 * n + lr;
        float b = sBias[col];
        float s = 0.f, q = 0.f;
        #pragma unroll
        for (int m = 0; m < 4; ++m)
            #pragma unroll
            for (int r = 0; r < 4; ++r) {
                float y = acc[m][n][r] + b;
                s += y; q += y * y;
                int row = 64 * wr + 16 * m + 4 * lg + r;
                sA[row * 192 + (col ^ ((row & 7) << 3))] = f2bf(y);
            }
        s += __shfl_xor(s, 16); s += __shfl_xor(s, 32);
        q += __shfl_xor(q, 16); q += __shfl_xor(q, 32);
        if (lg == 0) { atomicAdd(&sSQ[col], s); atomicAdd(&sSQ[128 + col], q); }
    }
    __syncthreads();
    #pragma unroll
    for (int i = tx; i < 2048; i += 512) {               // permuted row store
        int row = i >> 4, frag = i & 15;
        s16x8 v = *(const s16x8*)&sA[swz(row, frag * 8)];
        *(s16x8*)(ybuf + (size_t)sSlot[row] * 128 + frag * 8) = v;
    }
    if (tx < 256) atomicAdd(&pSQy[(blockIdx.x & 31) * 256 + tx], sSQ[tx]);
}

// ------------- Phase 3: vectorized gather + fused node BN stats --------------
// One wave per node; lane owns 8 cols (g=lane&7), rows split 8-way (rg).
__global__ __launch_bounds__(256) void k_gather(
    const short* __restrict__ ybuf, const int* __restrict__ startF,
    const float* __restrict__ st, float* __restrict__ pSQn,
    float* __restrict__ agg)
{
    __shared__ float sA_[128], sC_[128];
    __shared__ float sS[4][64], sQv[4][64];
    const int tx = threadIdx.x;
    if (tx < 128) { sA_[tx] = st[640 + tx]; sC_[tx] = st[768 + tx]; }
    __syncthreads();
    const int w = tx >> 6, l = tx & 63, g = l & 7, rg = l >> 3;
    const int n = blockIdx.x * 4 + w;
    const int s = startF[n], e2 = startF[n + 1];
    float am[8], cm[8], as2[8], cs2[8];
    #pragma unroll
    for (int t = 0; t < 8; ++t) {
        am[t] = sA_[8 * g + t];       cm[t] = sC_[8 * g + t];
        as2[t] = sA_[64 + 8 * g + t]; cs2[t] = sC_[64 + 8 * g + t];
    }
    float acc[8];
    #pragma unroll
    for (int t = 0; t < 8; ++t) acc[t] = 0.f;
    const short* base = ybuf + (size_t)s * 128;
    const int deg = e2 - s;
    for (int i = rg; i < deg; i += 8) {
        s16x8 ym8 = *(const s16x8*)(base + (size_t)i * 128 + g * 8);
        s16x8 ys8 = *(const s16x8*)(base + (size_t)i * 128 + 64 + g * 8);
        #pragma unroll
        for (int t = 0; t < 8; ++t)
            acc[t] += silu_f(fmaf(bf2f(ym8[t]), am[t], cm[t]))
                    * softplus_f(fmaf(bf2f(ys8[t]), as2[t], cs2[t]));
    }
    #pragma unroll
    for (int t = 0; t < 8; ++t) {                        // reduce row-groups
        acc[t] += __shfl_xor(acc[t], 8);
        acc[t] += __shfl_xor(acc[t], 16);
        acc[t] += __shfl_xor(acc[t], 32);
    }
    if (l < 8) {                                         // l == g here
        float4 f0 = {acc[0], acc[1], acc[2], acc[3]};
        float4 f1 = {acc[4], acc[5], acc[6], acc[7]};
        *(float4*)&agg[(size_t)n * 64 + g * 8] = f0;
        *(float4*)&agg[(size_t)n * 64 + g * 8 + 4] = f1;
        #pragma unroll
        for (int t = 0; t < 8; ++t) {
            sS[w][g * 8 + t] = acc[t];
            sQv[w][g * 8 + t] = acc[t] * acc[t];
        }
    }
    __syncthreads();
    if (tx < 64) {
        float s2 = sS[0][tx] + sS[1][tx] + sS[2][tx] + sS[3][tx];
        atomicAdd(&pSQn[(blockIdx.x & 31) * 128 + tx], s2);
    } else if (tx < 128) {
        int jj = tx - 64;
        float q2 = sQv[0][jj] + sQv[1][jj] + sQv[2][jj] + sQv[3][jj];
        atomicAdd(&pSQn[(blockIdx.x & 31) * 128 + 64 + jj], q2);
    }
}

// ------------- Phase 5: out = softplus(bn_n(agg) + nf), in place -------------
__global__ __launch_bounds__(256) void k_out(float* __restrict__ outagg,
                                             const float* __restrict__ nf,
                                             const float* __restrict__ st)
{
    long t = (long)blockIdx.x * 256 + threadIdx.x;
    int j = (int)(t & 63);
    float a = outagg[t];
    outagg[t] = softplus_f(fmaf(a, st[896 + j], st[960 + j]) + nf[t]);
}

extern "C" void kernel_launch(void* const* d_in, const int* in_sizes, int n_in,
                              void* d_out, int out_size, void* d_ws, size_t ws_size,
                              hipStream_t stream)
{
    (void)in_sizes; (void)n_in; (void)out_size; (void)ws_size;
    const float* nf  = (const float*)d_in[0];
    const float* ef  = (const float*)d_in[1];
    const int*   src = (const int*)d_in[2];
    const int*   dst = (const int*)d_in[3];
    const float* We  = (const float*)d_in[4];
    const float* be_ = (const float*)d_in[5];
    const float* ge  = (const float*)d_in[6];
    const float* bee = (const float*)d_in[7];
    const float* Wm  = (const float*)d_in[8];
    const float* bm  = (const float*)d_in[9];
    const float* gm  = (const float*)d_in[10];
    const float* bem = (const float*)d_in[11];
    const float* Ws  = (const float*)d_in[12];
    const float* bs  = (const float*)d_in[13];
    const float* gs  = (const float*)d_in[14];
    const float* bes = (const float*)d_in[15];
    const float* gn  = (const float*)d_in[16];
    const float* ben = (const float*)d_in[17];

    // ws layout
    float* st    = (float*)d_ws;
    short* xbuf  = (short*)((char*)d_ws + 4096);
    int*   startF= (int*)((char*)d_ws + 4096);            // overlays dead xbuf
    float* pSQn  = (float*)((char*)d_ws + 266240);        // overlays dead xbuf
    short* ybuf  = (short*)((char*)d_ws + 4096 + 102400000);

    // d_out scratch (dead before k_gather)
    char* ob = (char*)d_out;
    short* BT        = (short*)ob;
    short* BTe       = (short*)(ob + 49152);
    float* biasY     = (float*)(ob + 57344);
    int*   cnt       = (int*)(ob + 57856);
    int*   cur       = (int*)(ob + 257856);
    int*   slot      = (int*)(ob + 457856);
    int*   start_tmp = (int*)(ob + 3657856);
    short* nfb       = (short*)(ob + 3857920);
    float* pSQe      = (float*)(ob + 10257920);           // pSQy contiguous after
    float* agg       = (float*)d_out;

    hipMemsetAsync(cnt, 0, 200000, stream);

    // k_init: 3125 hist + 1563 nfb + 113 prep + 48 pSQ-zero = 4849 blocks
    k_init<<<4849, 256, 0, stream>>>(dst, cnt, nf, nfb,
                                     Wm, Ws, We, bm, bs, BT, BTe, biasY, pSQe);
    k_scan<<<1, 256, 0, stream>>>(cnt, start_tmp, cur);
    k_slot<<<3125, 256, 0, stream>>>(dst, cur, slot);

    k_xe_m<<<NE / 256, 512, 0, stream>>>(ef, BTe, be_, pSQe, xbuf);
    k_fin_r<<<1, 64, 0, stream>>>(pSQe, ge, bee, 1.0f / NE, 64, st + 512, st + 576);

    k_y_stats<<<NE / 128, 512, 0, stream>>>(nfb, src, dst, xbuf, BT, biasY, slot, st,
                                            pSQe + 4096 /* pSQy */, ybuf);

    // copy startF (xbuf now dead) + zero pSQn + finalize y-BNs, one launch
    k_post<<<213, 256, 0, stream>>>(start_tmp, startF, pSQn, pSQe + 4096,
                                    gm, bem, gs, bes, st + 640, st + 768);

    k_gather<<<NN / 4, 256, 0, stream>>>(ybuf, startF, st, pSQn, agg);
    k_fin_r<<<1, 64, 0, stream>>>(pSQn, gn, ben, 1.0f / NN, 64, st + 896, st + 960);

    k_out<<<NN * 64 / 256, 256, 0, stream>>>(agg, nf, st);
}